// Round 9
// baseline (458.114 us; speedup 1.0000x reference)
//
#include <hip/hip_runtime.h>
#include <math.h>

#define Bb   2
#define CIN  32
#define Gg   4
#define NH   4
#define Hh   28
#define Ww   28
#define HW   784
#define Pp   7
#define PP   49
#define MID  48
#define COUT 64
#define OC   192   // MID*NH

// workspace layout (units = u32 words / floats):
//   Qf16 [bh][g][ij][24 cpairs]   at QF    (8*4*784*24 = 602112)
//   Kf16 [bh][m][ij][24 cpairs]   at KF    (602112)
//   Vf16 [bh][mp][ij][48 ch]      at VF    (8*2*784*48 = 602112) m-pair packed
//   O f32 [b][v][ij][OC]          at OOFF  (1204224 floats)
#define QF    0
#define KF    602112
#define VF    1204224
#define OOFF  1806336
#define KBH   75264     // u32 per bh in K (4 m planes)
#define KM    18816     // u32 per m plane (784*24)
#define VBH   75264     // u32 per bh in V (2 planes)
#define VPL   37632     // u32 per V plane (784*48)

// 1/sqrt(32) * log2(e): K pre-scaled so softmax exp is a bare v_exp_f32.
#define KSCALE 0.2550611135387359f

// small precomputed tables
__device__ unsigned g_peT2[Gg * PP * 16];   // [v][kl][cpair(16)] — b128/lane coalesced
__device__ unsigned g_geT2[8 * 64];         // [cpair(8)][v*16+g*4+m], scaled
__device__ float    g_WT2[OC * COUT];       // [h*48+c][o], permuted Wout
// PERMUTED-transposed QKV weights: g_W*T[ci*192 + t] = W[oo(t)*CIN + ci],
// oo(t) = (t%48)*NH + t/48 — loads coalesced AND the (h=tid/48,c=tid%48)
// thread map keeps stores coalesced.
__device__ float    g_WqT[CIN * OC];
__device__ float    g_WkT[CIN * OC];
__device__ float    g_WvT[CIN * OC];

typedef _Float16 h2f __attribute__((ext_vector_type(2)));

__device__ __forceinline__ unsigned packh2(float a, float b) {
    auto r = __builtin_amdgcn_cvt_pkrtz(a, b);    // v_cvt_pkrtz_f16_f32
    return __builtin_bit_cast(unsigned, r);
}

__device__ __forceinline__ float fdot2(unsigned a, unsigned b, float c) {
    return __builtin_amdgcn_fdot2(__builtin_bit_cast(h2f, a),
                                  __builtin_bit_cast(h2f, b), c, false);
}

__device__ __forceinline__ float exp2_fast(float x) {   // 2^x, exp2(-inf)=0
    float r;
    asm("v_exp_f32 %0, %1" : "=v"(r) : "v"(x));
    return r;
}

// ---------------------------------------------------------------- kernel 0
// prep: permuted W transpose, 8 blocks. Separate kernel: qkvpe's conv blocks
// read g_W*T, and cross-block ordering within one launch is undefined.
__global__ __launch_bounds__(256) void prep_kernel(
    const float* __restrict__ Wq, const float* __restrict__ Wk,
    const float* __restrict__ Wv)
{
    int idx0 = blockIdx.x * 256 + threadIdx.x;
    for (int idx = idx0; idx < CIN * OC; idx += 8 * 256) {
        int t = idx % OC;                      // lane position in qkvpe
        int ci = idx / OC;
        int oo = (t % MID) * NH + t / MID;     // thread t's original channel
        int src = oo * CIN + ci;
        g_WqT[idx] = Wq[src];
        g_WkT[idx] = Wk[src];
        g_WvT[idx] = Wv[src];
    }
}

// ---------------------------------------------------------------- kernel 1
// QKV 1x1 conv, f16-packed output. Block = (b, g-pair, i, half-row of 14):
// 224 conv blocks + table block 224. Weights staged per-p in LDS
// (wls[32][193], lane-stride-1 conflict-free) — proven r8 structure.
__global__ __launch_bounds__(192) void qkvpe_kernel(const float* __restrict__ x,
    const float* __restrict__ bq, const float* __restrict__ bk,
    const float* __restrict__ bv,
    const float* row_w1, const float* row_b1,
    const float* row_g,  const float* row_bb,
    const float* row_w2, const float* row_b2,
    const float* col_w1, const float* col_b1,
    const float* col_g,  const float* col_bb,
    const float* col_w2, const float* col_b2,
    const float* row_idx, const float* col_idx,
    const float* group_emb, const int* g_indices,
    const float* Wout,
    float* __restrict__ ws)
{
    __shared__ float xs[2 * CIN * 16];            // 4 KB: two g-planes, stride 16
    __shared__ float wls[32 * 193];               // 24.7 KB: weights [ci][t] (also table staging)
    int tid = threadIdx.x;
    unsigned* uw = (unsigned*)ws;
    if (blockIdx.x == Bb * 2 * Hh * 2) {
        // ---------------- table block ----------------
        for (int t = tid; t < 2 * Gg * PP; t += 192) {
            int half = t / (Gg * PP);
            int n    = t - half * (Gg * PP);      // v*49 + kl
            int v = n / PP, kl = n % PP;
            const float* w1 = half ? col_w1 : row_w1;
            const float* b1 = half ? col_b1 : row_b1;
            const float* lg = half ? col_g  : row_g;
            const float* lb = half ? col_bb : row_bb;
            const float* w2 = half ? col_w2 : row_w2;
            const float* b2 = half ? col_b2 : row_b2;
            float tv = half ? col_idx[n] : row_idx[n];

            float hb[16];
            float mean = 0.f;
            for (int k = 0; k < 16; k++) { hb[k] = tv * w1[k] + b1[k]; mean += hb[k]; }
            mean *= (1.f / 16.f);
            float var = 0.f;
            for (int k = 0; k < 16; k++) { float d = hb[k] - mean; var += d * d; }
            var *= (1.f / 16.f);
            float inv = 1.f / sqrtf(var + 1e-5f);
            for (int k = 0; k < 16; k++) {
                float hn = (hb[k] - mean) * inv * lg[k] + lb[k];
                hb[k] = hn / (1.f + expf(-hn));
            }
            float accv[16];
            for (int p = 0; p < 16; p++) {
                float acc = b2[p];
                for (int k = 0; k < 16; k++) acc += hb[k] * w2[p * 16 + k];
                accv[p] = acc * KSCALE;
            }
            for (int i2 = 0; i2 < 8; i2++)
                g_peT2[(v * PP + kl) * 16 + half * 8 + i2] =
                    packh2(accv[2 * i2], accv[2 * i2 + 1]);
        }
        for (int t = tid; t < 64; t += 192) {
            int gi = g_indices[t];
            for (int i2 = 0; i2 < 8; i2++)
                g_geT2[i2 * 64 + t] = packh2(group_emb[gi * 16 + 2 * i2] * KSCALE,
                                             group_emb[gi * 16 + 2 * i2 + 1] * KSCALE);
        }
        // g_WT2[tp*64+o] = Wout[o*192 + c*4+h] via LDS transpose (wls as staging)
        for (int chunk = 0; chunk < 4; chunk++) {
            int obase = chunk * 16;
            __syncthreads();
            for (int idx = tid; idx < 16 * OC; idx += 192) {
                int ol = idx / OC, t = idx % OC;
                wls[ol * 193 + t] = Wout[(obase + ol) * OC + t];   // coalesced
            }
            __syncthreads();
            for (int idx = tid; idx < 16 * OC; idx += 192) {
                int tp = idx / 16, ol = idx % 16;                   // ol fastest
                int h = tp / MID, c = tp % MID;
                g_WT2[tp * 64 + obase + ol] = wls[ol * 193 + c * NH + h];
            }
        }
        return;
    }

    // ---------------- QKV block: (b, gp, i, half-row of 14), 2 g-planes ----
    int r = blockIdx.x;
    int jh = r & 1; r >>= 1;
    int i = r % Hh; r /= Hh;
    int gp = r & 1; int b = r >> 1;
    int j0 = jh * 14;

    for (int idx = tid; idx < 2 * CIN * 14; idx += 192) {
        int gs = idx / (CIN * 14), rem = idx % (CIN * 14);
        int ci = rem / 14, jj = rem % 14;
        xs[gs * CIN * 16 + ci * 16 + jj] =
            x[((b * CIN + ci) * Gg + 2 * gp + gs) * HW + i * Ww + j0 + jj];
    }

    int h = tid / MID, c = tid % MID;             // stores coalesced in c
    int oo = c * NH + h;
    int bh = b * NH + h;
    int ij0 = i * Ww + j0;
    const float* xs0 = &xs[0];
    const float* xs1 = &xs[CIN * 16];

// LDS-weight conv body: 14 positions from one g-plane, acc array A
#define CONVW(A, XR)                                                          \
    {                                                                         \
        _Pragma("unroll")                                                     \
        for (int jj = 0; jj < 14; jj++) A[jj] = bias;                         \
        _Pragma("unroll 4")                                                   \
        for (int ci = 0; ci < 32; ci++) {                                     \
            float wv = wls[ci * 193 + tid];                                   \
            float4 xA = *(const float4*)&XR[ci * 16 + 0];                     \
            float4 xB = *(const float4*)&XR[ci * 16 + 4];                     \
            float4 xC = *(const float4*)&XR[ci * 16 + 8];                     \
            float2 xD = *(const float2*)&XR[ci * 16 + 12];                    \
            A[0] += wv * xA.x;  A[1] += wv * xA.y;  A[2] += wv * xA.z;        \
            A[3] += wv * xA.w;  A[4] += wv * xB.x;  A[5] += wv * xB.y;        \
            A[6] += wv * xB.z;  A[7] += wv * xB.w;  A[8] += wv * xC.x;        \
            A[9] += wv * xC.y;  A[10] += wv * xC.z; A[11] += wv * xC.w;       \
            A[12] += wv * xD.x; A[13] += wv * xD.y;                           \
        }                                                                     \
    }

    #pragma unroll 1
    for (int p = 0; p < 3; p++) {
        const float* WT = (p == 0) ? g_WqT : (p == 1) ? g_WkT : g_WvT;
        float bias = ((p == 0) ? bq : (p == 1) ? bk : bv)[oo];
        __syncthreads();                           // prev-p wls reads done (also covers xs stage at p=0)
        #pragma unroll 4
        for (int ci = 0; ci < 32; ci++)
            wls[ci * 193 + tid] = WT[ci * OC + tid];   // coalesced global -> LDS
        __syncthreads();                           // wls ready

        if (p < 2) {
            float scl = p ? KSCALE : 1.0f;
            int base0 = p ? KF : QF;
            #pragma unroll 1
            for (int gs = 0; gs < 2; gs++) {
                float a[14];
                CONVW(a, (gs ? xs1 : xs0))
                int ob = base0 + ((bh * Gg + 2 * gp + gs) * HW + ij0) * 24 + (c >> 1);
                #pragma unroll
                for (int jj = 0; jj < 14; jj++) {
                    float av = a[jj] * scl;
                    float pr = __shfl_xor(av, 1, 64);   // partner channel c^1
                    if (!(tid & 1)) uw[ob + jj * 24] = packh2(av, pr);
                }
            }
        } else {
            float a0[14], a1[14];
            CONVW(a0, xs0)
            CONVW(a1, xs1)
            int vb = VF + ((bh * 2 + gp) * HW + ij0) * 48 + c;
            #pragma unroll
            for (int jj = 0; jj < 14; jj++)
                uw[vb + jj * 48] = packh2(a0[jj], a1[jj]);   // m-pair (g0,g1)
        }
    }
#undef CONVW
}

// ---------------------------------------------------------------- kernel 2
// attention: block = 4 waves = positions (i, j0..j0+3) for one (b,h).
// ROUND-21: pp2 LDS buffer ELIMINATED — packed probs stay in registers and
// PV sources them via __shfl(w, kl2) (compile-time lane -> v_readlane
// broadcast). LDS 37344 -> 31072 B => 5 blocks/CU (was 4, LDS-capped at
// 28% occupancy / 45% VALUBusy). Same 3 barriers (r14 showed extra barriers
// lose). PV runs branch-free on all 64 lanes (shfl source lane 48 must be
// active); only the final stores are lane-masked.
__global__ __launch_bounds__(256, 4) void attn_kernel(float* __restrict__ ws)
{
    __shared__ __align__(16) unsigned kvb[7000];   // 28000 B: K [m][cell][25]; V planes [2][cell][48]
    __shared__ __align__(16) unsigned qp[4][4][32];    // 2048 B: [wave][g][cpair 24, pad to 32]
    __shared__ __align__(16) float gsm[4][64];     //  1024 B: [wave][vg*4+m]

    const int tid  = threadIdx.x;
    const int wave = tid >> 6;
    const int lane = tid & 63;

    int blk = blockIdx.x;                  // ((bh)*28 + i)*7 + j0/4
    int j0 = (blk % 7) * 4;
    int i  = (blk / 7) % Hh;
    int bh = blk / (7 * Hh);
    int b = bh >> 2, h = bh & 3;
    int j  = j0 + wave;
    int ij = i * Ww + j;

    const unsigned* uw = (const unsigned*)ws;
    const unsigned* Kf = uw + KF + bh * KBH;
    const unsigned* Vf = uw + VF + bh * VBH;
    float* Ot = ws + OOFF;

    // ---- q f16 pairs straight from ws into per-wave LDS ----
    if (lane < 48) {
        int g = lane / 12, c4 = lane % 12;
        uint2 qv = *(const uint2*)&uw[QF + ((bh * Gg + g) * HW + ij) * 24 + c4 * 2];
        qp[wave][g][c4 * 2]     = qv.x;
        qp[wave][g][c4 * 2 + 1] = qv.y;
    }

    // ---- stage all-m K tile (f16 pairs in ws already): 420 slots of
    //      (cell, 8-channel chunk); clamped addresses, no zero-fill (OOB
    //      cells are masked to -inf downstream so garbage is harmless). ----
    #pragma unroll
    for (int s = 0; s < 2; s++) {
        int t = tid + s * 256;
        if (t < 420) {
            int c8 = t % 6, cl = t / 6;
            int gy = i - 3 + cl / 10, gx = j0 - 3 + cl % 10;
            gy = min(max(gy, 0), Hh - 1); gx = min(max(gx, 0), Ww - 1);
            const unsigned* kp = &Kf[(gy * Ww + gx) * 24 + c8 * 4];
            #pragma unroll
            for (int m = 0; m < 4; m++) {
                uint4 kv = *(const uint4*)(kp + m * KM);
                int o = (m * 70 + cl) * 25 + c8 * 4;
                *(uint2*)&kvb[o]     = make_uint2(kv.x, kv.y);
                *(uint2*)&kvb[o + 2] = make_uint2(kv.z, kv.w);
            }
        }
    }

    // ---- per-lane geometry (lane = kl) ----
    int kk = lane / Pp, ll = lane % Pp;
    int cell = (lane < PP) ? kk * 10 + ll + wave : 0;
    bool vmask = (lane < PP) && ((unsigned)(i + kk - 3) < Hh) && ((unsigned)(j + ll - 3) < Ww);
    int lclamp = lane < PP ? lane : 0;

    // ---- pe scores in registers; b128 q broadcasts + coalesced b128 peT2 ----
    float per[4][4] = {};                          // [v][g]
    #pragma unroll
    for (int u4 = 0; u4 < 4; u4++) {               // 4 cpairs per iter (c 0..31)
        uint4 qA = *(const uint4*)&qp[wave][0][u4 * 4];
        uint4 qB = *(const uint4*)&qp[wave][1][u4 * 4];
        uint4 qC = *(const uint4*)&qp[wave][2][u4 * 4];
        uint4 qD = *(const uint4*)&qp[wave][3][u4 * 4];
        #pragma unroll
        for (int v = 0; v < 4; v++) {
            uint4 pk = *(const uint4*)&g_peT2[(v * PP + lclamp) * 16 + u4 * 4];
            per[v][0] = fdot2(pk.w, qA.w, fdot2(pk.z, qA.z, fdot2(pk.y, qA.y, fdot2(pk.x, qA.x, per[v][0]))));
            per[v][1] = fdot2(pk.w, qB.w, fdot2(pk.z, qB.z, fdot2(pk.y, qB.y, fdot2(pk.x, qB.x, per[v][1]))));
            per[v][2] = fdot2(pk.w, qC.w, fdot2(pk.z, qC.z, fdot2(pk.y, qC.y, fdot2(pk.x, qC.x, per[v][2]))));
            per[v][3] = fdot2(pk.w, qD.w, fdot2(pk.z, qD.z, fdot2(pk.y, qD.y, fdot2(pk.x, qD.x, per[v][3]))));
        }
    }
    // fold the border/idle mask into per: exp2(-inf) = 0, so no per-term select
    if (!vmask) {
        #pragma unroll
        for (int v = 0; v < 4; v++)
            #pragma unroll
            for (int g = 0; g < 4; g++) per[v][g] = -INFINITY;
    }

    // ---- group scores: lane = vg*4+m; q pairs 16..23 (c 32..47) ----
    {
        int g = (lane >> 2) & 3;
        float ga = 0.f;
        #pragma unroll
        for (int u = 0; u < 8; u++)
            ga = fdot2(g_geT2[u * 64 + lane], qp[wave][g][16 + u], ga);
        gsm[wave][lane] = ga;
    }
    __syncthreads();                               // barrier 1: K tile ready

    // ---- content: b128 q broadcasts, b64 K reads; each K pair serves all 4 g ----
    float acc[4][4] = {};                          // [m][g]
    #pragma unroll 2
    for (int u4 = 0; u4 < 6; u4++) {               // 4 cpairs (8 channels) per iter
        uint4 qA = *(const uint4*)&qp[wave][0][u4 * 4];
        uint4 qB = *(const uint4*)&qp[wave][1][u4 * 4];
        uint4 qC = *(const uint4*)&qp[wave][2][u4 * 4];
        uint4 qD = *(const uint4*)&qp[wave][3][u4 * 4];
        #pragma unroll
        for (int m = 0; m < 4; m++) {
            int base = (m * 70 + cell) * 25 + u4 * 4;
            uint2 k01 = *(const uint2*)&kvb[base];
            uint2 k23 = *(const uint2*)&kvb[base + 2];
            acc[m][0] = fdot2(k23.y, qA.w, fdot2(k23.x, qA.z, fdot2(k01.y, qA.y, fdot2(k01.x, qA.x, acc[m][0]))));
            acc[m][1] = fdot2(k23.y, qB.w, fdot2(k23.x, qB.z, fdot2(k01.y, qB.y, fdot2(k01.x, qB.x, acc[m][1]))));
            acc[m][2] = fdot2(k23.y, qC.w, fdot2(k23.x, qC.z, fdot2(k01.y, qC.y, fdot2(k01.x, qC.x, acc[m][2]))));
            acc[m][3] = fdot2(k23.y, qD.w, fdot2(k23.x, qD.z, fdot2(k01.y, qD.y, fdot2(k01.x, qD.x, acc[m][3]))));
        }
    }

    // ---- softmax per (v,g); scores pre-scaled by log2e -> bare v_exp_f32 ----
    float ppr[4][4] = {};                          // [v][m]
    #pragma unroll
    for (int v = 0; v < 4; v++) {
        #pragma unroll
        for (int g = 0; g < 4; g++) {
            int vg = v * 4 + g;
            float4 gs = *(const float4*)&gsm[wave][vg * 4];   // b128 broadcast
            float ex[4];
            ex[0] = exp2_fast(acc[0][g] + per[v][g] + gs.x);
            ex[1] = exp2_fast(acc[1][g] + per[v][g] + gs.y);
            ex[2] = exp2_fast(acc[2][g] + per[v][g] + gs.z);
            ex[3] = exp2_fast(acc[3][g] + per[v][g] + gs.w);
            float ls = ex[0] + ex[1] + ex[2] + ex[3];
            #pragma unroll
            for (int d = 32; d > 0; d >>= 1) ls += __shfl_xor(ls, d, 64);
            float rinv = 1.0f / ls;
            #pragma unroll
            for (int m = 0; m < 4; m++) ppr[v][m] += ex[m] * rinv;
        }
    }
    // pack probs as f16 m-pairs — IN REGISTERS, all lanes (lanes>=49 hold
    // zeros: their ex[]=exp2(-inf)=0 -> ppr=0; they are never shfl-sourced).
    uint4 w0, w1;
    w0.x = packh2(ppr[0][0], ppr[0][1]); w0.y = packh2(ppr[0][2], ppr[0][3]);
    w0.z = packh2(ppr[1][0], ppr[1][1]); w0.w = packh2(ppr[1][2], ppr[1][3]);
    w1.x = packh2(ppr[2][0], ppr[2][1]); w1.y = packh2(ppr[2][2], ppr[2][3]);
    w1.z = packh2(ppr[3][0], ppr[3][1]); w1.w = packh2(ppr[3][2], ppr[3][3]);
    __syncthreads();                               // barrier 2: K reads done

    // ---- stage all-m V (f16 in ws already): direct load->LDS, both planes ----
    for (int t = tid; t < 840; t += 256) {
        int c4 = t % 12, cl = t / 12;
        int gy = i - 3 + cl / 10, gx = j0 - 3 + cl % 10;
        gy = min(max(gy, 0), Hh - 1); gx = min(max(gx, 0), Ww - 1);
        int off = (gy * Ww + gx) * 48 + c4 * 4;
        uint4 A = *(const uint4*)&Vf[off];
        uint4 B = *(const uint4*)&Vf[VPL + off];
        int o = cl * 48 + c4 * 4;
        *(uint4*)&kvb[o]        = A;
        *(uint4*)&kvb[3360 + o] = B;
    }
    __syncthreads();                               // barrier 3: V tile ready

    // ---- PV: ALL 64 lanes execute (shfl sources lanes 0..48); lane = c for
    //      the V reads (lanes 48-63 read in-bounds garbage, stores masked).
    //      Probs arrive via readlane broadcast — zero LDS traffic. ----
    {
        float o0 = 0.f, o1 = 0.f, o2 = 0.f, o3 = 0.f;
        const unsigned* v0b = &kvb[wave * 48 + lane];        // plane0 (m01)
        const unsigned* v1b = v0b + 3360;                    // plane1 (m23)
        #pragma unroll
        for (int kl2 = 0; kl2 < PP; kl2++) {
            int cellc = (kl2 / Pp) * 10 + (kl2 % Pp);        // compile-time
            unsigned vv0 = v0b[cellc * 48];
            unsigned vv1 = v1b[cellc * 48];
            unsigned ax = __shfl(w0.x, kl2, 64), ay = __shfl(w0.y, kl2, 64);
            unsigned az = __shfl(w0.z, kl2, 64), aw = __shfl(w0.w, kl2, 64);
            unsigned bx = __shfl(w1.x, kl2, 64), by = __shfl(w1.y, kl2, 64);
            unsigned bz = __shfl(w1.z, kl2, 64), bw = __shfl(w1.w, kl2, 64);
            o0 = fdot2(vv1, ay, fdot2(vv0, ax, o0));
            o1 = fdot2(vv1, aw, fdot2(vv0, az, o1));
            o2 = fdot2(vv1, by, fdot2(vv0, bx, o2));
            o3 = fdot2(vv1, bw, fdot2(vv0, bz, o3));
        }
        if (lane < MID) {
            Ot[((size_t)(b * Gg + 0) * HW + ij) * OC + h * MID + lane] = o0;
            Ot[((size_t)(b * Gg + 1) * HW + ij) * OC + h * MID + lane] = o1;
            Ot[((size_t)(b * Gg + 2) * HW + ij) * OC + h * MID + lane] = o2;
            Ot[((size_t)(b * Gg + 3) * HW + ij) * OC + h * MID + lane] = o3;
        }
    }
}

// ---------------------------------------------------------------- kernel 3
__global__ __launch_bounds__(256) void outproj_kernel(const float* __restrict__ bout,
                                                      const float* __restrict__ ws,
                                                      float* __restrict__ out)
{
    __shared__ float ov[16 * 193];
    __shared__ float res[64 * 17];
    int tid = threadIdx.x;
    int p0 = blockIdx.x * 16;
    const float* Ot = ws + OOFF;

    for (int idx = tid; idx < 16 * OC; idx += 256) {
        int pl = idx / OC, t = idx % OC;
        ov[pl * 193 + t] = Ot[(size_t)(p0 + pl) * OC + t];
    }
    __syncthreads();

    int o = tid & 63, pg = tid >> 6;
    float a0 = bout[o], a1 = a0, a2 = a0, a3 = a0;
    #pragma unroll 8
    for (int t = 0; t < OC; t++) {
        float w = g_WT2[t * 64 + o];
        a0 += w * ov[(pg     ) * 193 + t];
        a1 += w * ov[(pg +  4) * 193 + t];
        a2 += w * ov[(pg +  8) * 193 + t];
        a3 += w * ov[(pg + 12) * 193 + t];
    }
    res[o * 17 + pg     ] = a0;
    res[o * 17 + pg +  4] = a1;
    res[o * 17 + pg +  8] = a2;
    res[o * 17 + pg + 12] = a3;
    __syncthreads();

    for (int idx = tid; idx < 1024; idx += 256) {
        int o2 = idx >> 4, pl = idx & 15;
        int p = p0 + pl;
        int ij2 = p % HW; int bv = p / HW; int v = bv & 3; int bb = bv >> 2;
        out[((bb * COUT + o2) * Gg + v) * HW + ij2] = res[o2 * 17 + pl];
    }
}

// ---------------------------------------------------------------- launch
extern "C" void kernel_launch(void* const* d_in, const int* in_sizes, int n_in,
                              void* d_out, int out_size, void* d_ws, size_t ws_size,
                              hipStream_t stream)
{
    const float* x      = (const float*)d_in[0];
    const float* Wq     = (const float*)d_in[1];
    const float* bq     = (const float*)d_in[2];
    const float* Wk     = (const float*)d_in[3];
    const float* bk     = (const float*)d_in[4];
    const float* Wv     = (const float*)d_in[5];
    const float* bv     = (const float*)d_in[6];
    const float* Wout   = (const float*)d_in[7];
    const float* bout   = (const float*)d_in[8];
    const float* row_w1 = (const float*)d_in[9];
    const float* row_b1 = (const float*)d_in[10];
    const float* row_g  = (const float*)d_in[11];
    const float* row_bb = (const float*)d_in[12];
    const float* row_w2 = (const float*)d_in[13];
    const float* row_b2 = (const float*)d_in[14];
    const float* col_w1 = (const float*)d_in[15];
    const float* col_b1 = (const float*)d_in[16];
    const float* col_g  = (const float*)d_in[17];
    const float* col_bb = (const float*)d_in[18];
    const float* col_w2 = (const float*)d_in[19];
    const float* col_b2 = (const float*)d_in[20];
    const float* gemb   = (const float*)d_in[21];
    const float* ridx   = (const float*)d_in[22];
    const float* cidx   = (const float*)d_in[23];
    const int*   gidx   = (const int*)d_in[24];

    float* ws  = (float*)d_ws;
    float* out = (float*)d_out;

    prep_kernel<<<8, 256, 0, stream>>>(Wq, Wk, Wv);
    qkvpe_kernel<<<Bb * 2 * Hh * 2 + 1, 192, 0, stream>>>(
        x, bq, bk, bv,
        row_w1, row_b1, row_g, row_bb, row_w2, row_b2,
        col_w1, col_b1, col_g, col_bb, col_w2, col_b2,
        ridx, cidx, gemb, gidx, Wout, ws);
    attn_kernel<<<Bb * NH * Hh * (Ww / 4), 256, 0, stream>>>(ws);
    outproj_kernel<<<Bb * Gg * HW / 16, 256, 0, stream>>>(bout, ws, out);
}

// Round 10
// 179.238 us; speedup vs baseline: 2.5559x; 2.5559x over previous
//
#include <hip/hip_runtime.h>
#include <math.h>

#define Bb   2
#define CIN  32
#define Gg   4
#define NH   4
#define Hh   28
#define Ww   28
#define HW   784
#define Pp   7
#define PP   49
#define MID  48
#define COUT 64
#define OC   192   // MID*NH

// workspace layout (units = u32 words / floats):
//   Qf16 [bh][g][ij][24 cpairs]   at QF    (8*4*784*24 = 602112)
//   Kf16 [bh][m][ij][24 cpairs]   at KF    (602112)
//   Vf16 [bh][mp][ij][48 ch]      at VF    (8*2*784*48 = 602112) m-pair packed
//   O f32 [b][v][ij][OC]          at OOFF  (1204224 floats)
#define QF    0
#define KF    602112
#define VF    1204224
#define OOFF  1806336
#define KBH   75264     // u32 per bh in K (4 m planes)
#define KM    18816     // u32 per m plane (784*24)
#define VBH   75264     // u32 per bh in V (2 planes)
#define VPL   37632     // u32 per V plane (784*48)

// 1/sqrt(32) * log2(e): K pre-scaled so softmax exp is a bare v_exp_f32.
#define KSCALE 0.2550611135387359f

// small precomputed tables
__device__ unsigned g_peT2[Gg * PP * 16];   // [v][kl][cpair(16)] — b128/lane coalesced
__device__ unsigned g_geT2[8 * 64];         // [cpair(8)][v*16+g*4+m], scaled
__device__ float    g_WT2[OC * COUT];       // [h*48+c][o], permuted Wout
// PERMUTED-transposed QKV weights: g_W*T[ci*192 + t] = W[oo(t)*CIN + ci],
// oo(t) = (t%48)*NH + t/48 — loads coalesced AND the (h=tid/48,c=tid%48)
// thread map keeps stores coalesced.
__device__ float    g_WqT[CIN * OC];
__device__ float    g_WkT[CIN * OC];
__device__ float    g_WvT[CIN * OC];

typedef _Float16 h2f __attribute__((ext_vector_type(2)));

__device__ __forceinline__ unsigned packh2(float a, float b) {
    auto r = __builtin_amdgcn_cvt_pkrtz(a, b);    // v_cvt_pkrtz_f16_f32
    return __builtin_bit_cast(unsigned, r);
}

__device__ __forceinline__ float fdot2(unsigned a, unsigned b, float c) {
    return __builtin_amdgcn_fdot2(__builtin_bit_cast(h2f, a),
                                  __builtin_bit_cast(h2f, b), c, false);
}

__device__ __forceinline__ float exp2_fast(float x) {   // 2^x, exp2(-inf)=0
    float r;
    asm("v_exp_f32 %0, %1" : "=v"(r) : "v"(x));
    return r;
}

// ---------------------------------------------------------------- kernel 0
// prep: permuted W transpose, 8 blocks. Separate kernel: qkvpe's conv blocks
// read g_W*T, and cross-block ordering within one launch is undefined.
__global__ __launch_bounds__(256) void prep_kernel(
    const float* __restrict__ Wq, const float* __restrict__ Wk,
    const float* __restrict__ Wv)
{
    int idx0 = blockIdx.x * 256 + threadIdx.x;
    for (int idx = idx0; idx < CIN * OC; idx += 8 * 256) {
        int t = idx % OC;                      // lane position in qkvpe
        int ci = idx / OC;
        int oo = (t % MID) * NH + t / MID;     // thread t's original channel
        int src = oo * CIN + ci;
        g_WqT[idx] = Wq[src];
        g_WkT[idx] = Wk[src];
        g_WvT[idx] = Wv[src];
    }
}

// ---------------------------------------------------------------- kernel 1
// QKV 1x1 conv, f16-packed output. Block = (b, g-pair, i, half-row of 14):
// 224 conv blocks + table block 224. Weights staged per-p in LDS
// (wls[32][193], lane-stride-1 conflict-free) — proven r8 structure.
// SESSION LAW (r15/r17/r7/r9): any structure that materializes a large pool
// of independent/loop-invariant values (reg prefetch arrays, reg weights,
// hoisted shfl broadcasts) spills to scratch on this kernel family. Bulk
// data goes through LDS only.
__global__ __launch_bounds__(192) void qkvpe_kernel(const float* __restrict__ x,
    const float* __restrict__ bq, const float* __restrict__ bk,
    const float* __restrict__ bv,
    const float* row_w1, const float* row_b1,
    const float* row_g,  const float* row_bb,
    const float* row_w2, const float* row_b2,
    const float* col_w1, const float* col_b1,
    const float* col_g,  const float* col_bb,
    const float* col_w2, const float* col_b2,
    const float* row_idx, const float* col_idx,
    const float* group_emb, const int* g_indices,
    const float* Wout,
    float* __restrict__ ws)
{
    __shared__ float xs[2 * CIN * 16];            // 4 KB: two g-planes, stride 16
    __shared__ float wls[32 * 193];               // 24.7 KB: weights [ci][t] (also table staging)
    int tid = threadIdx.x;
    unsigned* uw = (unsigned*)ws;
    if (blockIdx.x == Bb * 2 * Hh * 2) {
        // ---------------- table block ----------------
        for (int t = tid; t < 2 * Gg * PP; t += 192) {
            int half = t / (Gg * PP);
            int n    = t - half * (Gg * PP);      // v*49 + kl
            int v = n / PP, kl = n % PP;
            const float* w1 = half ? col_w1 : row_w1;
            const float* b1 = half ? col_b1 : row_b1;
            const float* lg = half ? col_g  : row_g;
            const float* lb = half ? col_bb : row_bb;
            const float* w2 = half ? col_w2 : row_w2;
            const float* b2 = half ? col_b2 : row_b2;
            float tv = half ? col_idx[n] : row_idx[n];

            float hb[16];
            float mean = 0.f;
            for (int k = 0; k < 16; k++) { hb[k] = tv * w1[k] + b1[k]; mean += hb[k]; }
            mean *= (1.f / 16.f);
            float var = 0.f;
            for (int k = 0; k < 16; k++) { float d = hb[k] - mean; var += d * d; }
            var *= (1.f / 16.f);
            float inv = 1.f / sqrtf(var + 1e-5f);
            for (int k = 0; k < 16; k++) {
                float hn = (hb[k] - mean) * inv * lg[k] + lb[k];
                hb[k] = hn / (1.f + expf(-hn));
            }
            float accv[16];
            for (int p = 0; p < 16; p++) {
                float acc = b2[p];
                for (int k = 0; k < 16; k++) acc += hb[k] * w2[p * 16 + k];
                accv[p] = acc * KSCALE;
            }
            for (int i2 = 0; i2 < 8; i2++)
                g_peT2[(v * PP + kl) * 16 + half * 8 + i2] =
                    packh2(accv[2 * i2], accv[2 * i2 + 1]);
        }
        for (int t = tid; t < 64; t += 192) {
            int gi = g_indices[t];
            for (int i2 = 0; i2 < 8; i2++)
                g_geT2[i2 * 64 + t] = packh2(group_emb[gi * 16 + 2 * i2] * KSCALE,
                                             group_emb[gi * 16 + 2 * i2 + 1] * KSCALE);
        }
        // g_WT2[tp*64+o] = Wout[o*192 + c*4+h] via LDS transpose (wls as staging)
        for (int chunk = 0; chunk < 4; chunk++) {
            int obase = chunk * 16;
            __syncthreads();
            for (int idx = tid; idx < 16 * OC; idx += 192) {
                int ol = idx / OC, t = idx % OC;
                wls[ol * 193 + t] = Wout[(obase + ol) * OC + t];   // coalesced
            }
            __syncthreads();
            for (int idx = tid; idx < 16 * OC; idx += 192) {
                int tp = idx / 16, ol = idx % 16;                   // ol fastest
                int h = tp / MID, c = tp % MID;
                g_WT2[tp * 64 + obase + ol] = wls[ol * 193 + c * NH + h];
            }
        }
        return;
    }

    // ---------------- QKV block: (b, gp, i, half-row of 14), 2 g-planes ----
    int r = blockIdx.x;
    int jh = r & 1; r >>= 1;
    int i = r % Hh; r /= Hh;
    int gp = r & 1; int b = r >> 1;
    int j0 = jh * 14;

    for (int idx = tid; idx < 2 * CIN * 14; idx += 192) {
        int gs = idx / (CIN * 14), rem = idx % (CIN * 14);
        int ci = rem / 14, jj = rem % 14;
        xs[gs * CIN * 16 + ci * 16 + jj] =
            x[((b * CIN + ci) * Gg + 2 * gp + gs) * HW + i * Ww + j0 + jj];
    }

    int h = tid / MID, c = tid % MID;             // stores coalesced in c
    int oo = c * NH + h;
    int bh = b * NH + h;
    int ij0 = i * Ww + j0;
    const float* xs0 = &xs[0];
    const float* xs1 = &xs[CIN * 16];

// LDS-weight conv body: 14 positions from one g-plane, acc array A
#define CONVW(A, XR)                                                          \
    {                                                                         \
        _Pragma("unroll")                                                     \
        for (int jj = 0; jj < 14; jj++) A[jj] = bias;                         \
        _Pragma("unroll 4")                                                   \
        for (int ci = 0; ci < 32; ci++) {                                     \
            float wv = wls[ci * 193 + tid];                                   \
            float4 xA = *(const float4*)&XR[ci * 16 + 0];                     \
            float4 xB = *(const float4*)&XR[ci * 16 + 4];                     \
            float4 xC = *(const float4*)&XR[ci * 16 + 8];                     \
            float2 xD = *(const float2*)&XR[ci * 16 + 12];                    \
            A[0] += wv * xA.x;  A[1] += wv * xA.y;  A[2] += wv * xA.z;        \
            A[3] += wv * xA.w;  A[4] += wv * xB.x;  A[5] += wv * xB.y;        \
            A[6] += wv * xB.z;  A[7] += wv * xB.w;  A[8] += wv * xC.x;        \
            A[9] += wv * xC.y;  A[10] += wv * xC.z; A[11] += wv * xC.w;       \
            A[12] += wv * xD.x; A[13] += wv * xD.y;                           \
        }                                                                     \
    }

    #pragma unroll 1
    for (int p = 0; p < 3; p++) {
        const float* WT = (p == 0) ? g_WqT : (p == 1) ? g_WkT : g_WvT;
        float bias = ((p == 0) ? bq : (p == 1) ? bk : bv)[oo];
        __syncthreads();                           // prev-p wls reads done (also covers xs stage at p=0)
        #pragma unroll 4
        for (int ci = 0; ci < 32; ci++)
            wls[ci * 193 + tid] = WT[ci * OC + tid];   // coalesced global -> LDS
        __syncthreads();                           // wls ready

        if (p < 2) {
            float scl = p ? KSCALE : 1.0f;
            int base0 = p ? KF : QF;
            #pragma unroll 1
            for (int gs = 0; gs < 2; gs++) {
                float a[14];
                CONVW(a, (gs ? xs1 : xs0))
                int ob = base0 + ((bh * Gg + 2 * gp + gs) * HW + ij0) * 24 + (c >> 1);
                #pragma unroll
                for (int jj = 0; jj < 14; jj++) {
                    float av = a[jj] * scl;
                    float pr = __shfl_xor(av, 1, 64);   // partner channel c^1
                    if (!(tid & 1)) uw[ob + jj * 24] = packh2(av, pr);
                }
            }
        } else {
            float a0[14], a1[14];
            CONVW(a0, xs0)
            CONVW(a1, xs1)
            int vb = VF + ((bh * 2 + gp) * HW + ij0) * 48 + c;
            #pragma unroll
            for (int jj = 0; jj < 14; jj++)
                uw[vb + jj * 48] = packh2(a0[jj], a1[jj]);   // m-pair (g0,g1)
        }
    }
#undef CONVW
}

// ---------------------------------------------------------------- kernel 2
// attention: block = 4 waves = positions (i, j0..j0+3) for one (b,h).
// r8-verified form: f16 ws staging, clamped addresses, pp2 prob transport
// through LDS (r9's register/shfl transport LICM-hoisted 392 broadcasts ->
// 680 MB scratch traffic; LDS is the only safe bulk path here).
__global__ __launch_bounds__(256, 4) void attn_kernel(float* __restrict__ ws)
{
    __shared__ __align__(16) unsigned kvb[7000];   // 28000 B: K [m][cell][25]; V planes [2][cell][48]
    __shared__ __align__(16) unsigned pp2[4][PP][8];   // 6272 B: [wave][kl][v*2+mp] f16-pair probs
    __shared__ __align__(16) unsigned qp[4][4][32];    // 2048 B: [wave][g][cpair 24, pad to 32]
    __shared__ __align__(16) float gsm[4][64];     //  1024 B: [wave][vg*4+m]

    const int tid  = threadIdx.x;
    const int wave = tid >> 6;
    const int lane = tid & 63;

    int blk = blockIdx.x;                  // ((bh)*28 + i)*7 + j0/4
    int j0 = (blk % 7) * 4;
    int i  = (blk / 7) % Hh;
    int bh = blk / (7 * Hh);
    int b = bh >> 2, h = bh & 3;
    int j  = j0 + wave;
    int ij = i * Ww + j;

    const unsigned* uw = (const unsigned*)ws;
    const unsigned* Kf = uw + KF + bh * KBH;
    const unsigned* Vf = uw + VF + bh * VBH;
    float* Ot = ws + OOFF;

    // ---- q f16 pairs straight from ws into per-wave LDS ----
    if (lane < 48) {
        int g = lane / 12, c4 = lane % 12;
        uint2 qv = *(const uint2*)&uw[QF + ((bh * Gg + g) * HW + ij) * 24 + c4 * 2];
        qp[wave][g][c4 * 2]     = qv.x;
        qp[wave][g][c4 * 2 + 1] = qv.y;
    }

    // ---- stage all-m K tile (f16 pairs in ws already): 420 slots of
    //      (cell, 8-channel chunk); clamped addresses, no zero-fill (OOB
    //      cells are masked to -inf downstream so garbage is harmless). ----
    #pragma unroll
    for (int s = 0; s < 2; s++) {
        int t = tid + s * 256;
        if (t < 420) {
            int c8 = t % 6, cl = t / 6;
            int gy = i - 3 + cl / 10, gx = j0 - 3 + cl % 10;
            gy = min(max(gy, 0), Hh - 1); gx = min(max(gx, 0), Ww - 1);
            const unsigned* kp = &Kf[(gy * Ww + gx) * 24 + c8 * 4];
            #pragma unroll
            for (int m = 0; m < 4; m++) {
                uint4 kv = *(const uint4*)(kp + m * KM);
                int o = (m * 70 + cl) * 25 + c8 * 4;
                *(uint2*)&kvb[o]     = make_uint2(kv.x, kv.y);
                *(uint2*)&kvb[o + 2] = make_uint2(kv.z, kv.w);
            }
        }
    }

    // ---- per-lane geometry (lane = kl) ----
    int kk = lane / Pp, ll = lane % Pp;
    int cell = (lane < PP) ? kk * 10 + ll + wave : 0;
    bool vmask = (lane < PP) && ((unsigned)(i + kk - 3) < Hh) && ((unsigned)(j + ll - 3) < Ww);
    int lclamp = lane < PP ? lane : 0;

    // ---- pe scores in registers; b128 q broadcasts + coalesced b128 peT2 ----
    float per[4][4] = {};                          // [v][g]
    #pragma unroll
    for (int u4 = 0; u4 < 4; u4++) {               // 4 cpairs per iter (c 0..31)
        uint4 qA = *(const uint4*)&qp[wave][0][u4 * 4];
        uint4 qB = *(const uint4*)&qp[wave][1][u4 * 4];
        uint4 qC = *(const uint4*)&qp[wave][2][u4 * 4];
        uint4 qD = *(const uint4*)&qp[wave][3][u4 * 4];
        #pragma unroll
        for (int v = 0; v < 4; v++) {
            uint4 pk = *(const uint4*)&g_peT2[(v * PP + lclamp) * 16 + u4 * 4];
            per[v][0] = fdot2(pk.w, qA.w, fdot2(pk.z, qA.z, fdot2(pk.y, qA.y, fdot2(pk.x, qA.x, per[v][0]))));
            per[v][1] = fdot2(pk.w, qB.w, fdot2(pk.z, qB.z, fdot2(pk.y, qB.y, fdot2(pk.x, qB.x, per[v][1]))));
            per[v][2] = fdot2(pk.w, qC.w, fdot2(pk.z, qC.z, fdot2(pk.y, qC.y, fdot2(pk.x, qC.x, per[v][2]))));
            per[v][3] = fdot2(pk.w, qD.w, fdot2(pk.z, qD.z, fdot2(pk.y, qD.y, fdot2(pk.x, qD.x, per[v][3]))));
        }
    }
    // fold the border/idle mask into per: exp2(-inf) = 0, so no per-term select
    if (!vmask) {
        #pragma unroll
        for (int v = 0; v < 4; v++)
            #pragma unroll
            for (int g = 0; g < 4; g++) per[v][g] = -INFINITY;
    }

    // ---- group scores: lane = vg*4+m; q pairs 16..23 (c 32..47) ----
    {
        int g = (lane >> 2) & 3;
        float ga = 0.f;
        #pragma unroll
        for (int u = 0; u < 8; u++)
            ga = fdot2(g_geT2[u * 64 + lane], qp[wave][g][16 + u], ga);
        gsm[wave][lane] = ga;
    }
    __syncthreads();                               // barrier 1: K tile ready

    // ---- content: b128 q broadcasts, b64 K reads; each K pair serves all 4 g ----
    float acc[4][4] = {};                          // [m][g]
    #pragma unroll 2
    for (int u4 = 0; u4 < 6; u4++) {               // 4 cpairs (8 channels) per iter
        uint4 qA = *(const uint4*)&qp[wave][0][u4 * 4];
        uint4 qB = *(const uint4*)&qp[wave][1][u4 * 4];
        uint4 qC = *(const uint4*)&qp[wave][2][u4 * 4];
        uint4 qD = *(const uint4*)&qp[wave][3][u4 * 4];
        #pragma unroll
        for (int m = 0; m < 4; m++) {
            int base = (m * 70 + cell) * 25 + u4 * 4;
            uint2 k01 = *(const uint2*)&kvb[base];
            uint2 k23 = *(const uint2*)&kvb[base + 2];
            acc[m][0] = fdot2(k23.y, qA.w, fdot2(k23.x, qA.z, fdot2(k01.y, qA.y, fdot2(k01.x, qA.x, acc[m][0]))));
            acc[m][1] = fdot2(k23.y, qB.w, fdot2(k23.x, qB.z, fdot2(k01.y, qB.y, fdot2(k01.x, qB.x, acc[m][1]))));
            acc[m][2] = fdot2(k23.y, qC.w, fdot2(k23.x, qC.z, fdot2(k01.y, qC.y, fdot2(k01.x, qC.x, acc[m][2]))));
            acc[m][3] = fdot2(k23.y, qD.w, fdot2(k23.x, qD.z, fdot2(k01.y, qD.y, fdot2(k01.x, qD.x, acc[m][3]))));
        }
    }

    // ---- softmax per (v,g); scores pre-scaled by log2e -> bare v_exp_f32 ----
    float ppr[4][4] = {};                          // [v][m]
    #pragma unroll
    for (int v = 0; v < 4; v++) {
        #pragma unroll
        for (int g = 0; g < 4; g++) {
            int vg = v * 4 + g;
            float4 gs = *(const float4*)&gsm[wave][vg * 4];   // b128 broadcast
            float ex[4];
            ex[0] = exp2_fast(acc[0][g] + per[v][g] + gs.x);
            ex[1] = exp2_fast(acc[1][g] + per[v][g] + gs.y);
            ex[2] = exp2_fast(acc[2][g] + per[v][g] + gs.z);
            ex[3] = exp2_fast(acc[3][g] + per[v][g] + gs.w);
            float ls = ex[0] + ex[1] + ex[2] + ex[3];
            #pragma unroll
            for (int d = 32; d > 0; d >>= 1) ls += __shfl_xor(ls, d, 64);
            float rinv = 1.0f / ls;
            #pragma unroll
            for (int m = 0; m < 4; m++) ppr[v][m] += ex[m] * rinv;
        }
    }
    // pack probs as f16 m-pairs: pp2[wave][kl][v*2+mp]
    if (lane < PP) {
        uint4 w0, w1;
        w0.x = packh2(ppr[0][0], ppr[0][1]); w0.y = packh2(ppr[0][2], ppr[0][3]);
        w0.z = packh2(ppr[1][0], ppr[1][1]); w0.w = packh2(ppr[1][2], ppr[1][3]);
        w1.x = packh2(ppr[2][0], ppr[2][1]); w1.y = packh2(ppr[2][2], ppr[2][3]);
        w1.z = packh2(ppr[3][0], ppr[3][1]); w1.w = packh2(ppr[3][2], ppr[3][3]);
        *(uint4*)&pp2[wave][lane][0] = w0;
        *(uint4*)&pp2[wave][lane][4] = w1;
    }
    __syncthreads();                               // barrier 2: K reads done

    // ---- stage all-m V (f16 in ws already): direct load->LDS, both planes ----
    for (int t = tid; t < 840; t += 256) {
        int c4 = t % 12, cl = t / 12;
        int gy = i - 3 + cl / 10, gx = j0 - 3 + cl % 10;
        gy = min(max(gy, 0), Hh - 1); gx = min(max(gx, 0), Ww - 1);
        int off = (gy * Ww + gx) * 48 + c4 * 4;
        uint4 A = *(const uint4*)&Vf[off];
        uint4 B = *(const uint4*)&Vf[VPL + off];
        int o = cl * 48 + c4 * 4;
        *(uint4*)&kvb[o]        = A;
        *(uint4*)&kvb[3360 + o] = B;
    }
    __syncthreads();                               // barrier 3: V tile ready

    // ---- PV: lane = c (<48); two b32 plane reads (<=2-way, free) + 2 b128
    //      prob broadcasts per cell; fully unrolled -> all-immediate offsets ----
    if (lane < MID) {
        float o0 = 0.f, o1 = 0.f, o2 = 0.f, o3 = 0.f;
        const uint4* ppw = (const uint4*)&pp2[wave][0][0];
        const unsigned* v0b = &kvb[wave * 48 + lane];        // plane0 (m01)
        const unsigned* v1b = v0b + 3360;                    // plane1 (m23)
        #pragma unroll
        for (int kl2 = 0; kl2 < PP; kl2++) {
            int cellc = (kl2 / Pp) * 10 + (kl2 % Pp);        // compile-time
            unsigned vv0 = v0b[cellc * 48];
            unsigned vv1 = v1b[cellc * 48];
            uint4 A = ppw[kl2 * 2];
            uint4 B = ppw[kl2 * 2 + 1];
            o0 = fdot2(vv1, A.y, fdot2(vv0, A.x, o0));
            o1 = fdot2(vv1, A.w, fdot2(vv0, A.z, o1));
            o2 = fdot2(vv1, B.y, fdot2(vv0, B.x, o2));
            o3 = fdot2(vv1, B.w, fdot2(vv0, B.z, o3));
        }
        Ot[((size_t)(b * Gg + 0) * HW + ij) * OC + h * MID + lane] = o0;
        Ot[((size_t)(b * Gg + 1) * HW + ij) * OC + h * MID + lane] = o1;
        Ot[((size_t)(b * Gg + 2) * HW + ij) * OC + h * MID + lane] = o2;
        Ot[((size_t)(b * Gg + 3) * HW + ij) * OC + h * MID + lane] = o3;
    }
}

// ---------------------------------------------------------------- kernel 3
__global__ __launch_bounds__(256) void outproj_kernel(const float* __restrict__ bout,
                                                      const float* __restrict__ ws,
                                                      float* __restrict__ out)
{
    __shared__ float ov[16 * 193];
    __shared__ float res[64 * 17];
    int tid = threadIdx.x;
    int p0 = blockIdx.x * 16;
    const float* Ot = ws + OOFF;

    for (int idx = tid; idx < 16 * OC; idx += 256) {
        int pl = idx / OC, t = idx % OC;
        ov[pl * 193 + t] = Ot[(size_t)(p0 + pl) * OC + t];
    }
    __syncthreads();

    int o = tid & 63, pg = tid >> 6;
    float a0 = bout[o], a1 = a0, a2 = a0, a3 = a0;
    #pragma unroll 8
    for (int t = 0; t < OC; t++) {
        float w = g_WT2[t * 64 + o];
        a0 += w * ov[(pg     ) * 193 + t];
        a1 += w * ov[(pg +  4) * 193 + t];
        a2 += w * ov[(pg +  8) * 193 + t];
        a3 += w * ov[(pg + 12) * 193 + t];
    }
    res[o * 17 + pg     ] = a0;
    res[o * 17 + pg +  4] = a1;
    res[o * 17 + pg +  8] = a2;
    res[o * 17 + pg + 12] = a3;
    __syncthreads();

    for (int idx = tid; idx < 1024; idx += 256) {
        int o2 = idx >> 4, pl = idx & 15;
        int p = p0 + pl;
        int ij2 = p % HW; int bv = p / HW; int v = bv & 3; int bb = bv >> 2;
        out[((bb * COUT + o2) * Gg + v) * HW + ij2] = res[o2 * 17 + pl];
    }
}

// ---------------------------------------------------------------- launch
extern "C" void kernel_launch(void* const* d_in, const int* in_sizes, int n_in,
                              void* d_out, int out_size, void* d_ws, size_t ws_size,
                              hipStream_t stream)
{
    const float* x      = (const float*)d_in[0];
    const float* Wq     = (const float*)d_in[1];
    const float* bq     = (const float*)d_in[2];
    const float* Wk     = (const float*)d_in[3];
    const float* bk     = (const float*)d_in[4];
    const float* Wv     = (const float*)d_in[5];
    const float* bv     = (const float*)d_in[6];
    const float* Wout   = (const float*)d_in[7];
    const float* bout   = (const float*)d_in[8];
    const float* row_w1 = (const float*)d_in[9];
    const float* row_b1 = (const float*)d_in[10];
    const float* row_g  = (const float*)d_in[11];
    const float* row_bb = (const float*)d_in[12];
    const float* row_w2 = (const float*)d_in[13];
    const float* row_b2 = (const float*)d_in[14];
    const float* col_w1 = (const float*)d_in[15];
    const float* col_b1 = (const float*)d_in[16];
    const float* col_g  = (const float*)d_in[17];
    const float* col_bb = (const float*)d_in[18];
    const float* col_w2 = (const float*)d_in[19];
    const float* col_b2 = (const float*)d_in[20];
    const float* gemb   = (const float*)d_in[21];
    const float* ridx   = (const float*)d_in[22];
    const float* cidx   = (const float*)d_in[23];
    const int*   gidx   = (const int*)d_in[24];

    float* ws  = (float*)d_ws;
    float* out = (float*)d_out;

    prep_kernel<<<8, 256, 0, stream>>>(Wq, Wk, Wv);
    qkvpe_kernel<<<Bb * 2 * Hh * 2 + 1, 192, 0, stream>>>(
        x, bq, bk, bv,
        row_w1, row_b1, row_g, row_bb, row_w2, row_b2,
        col_w1, col_b1, col_g, col_bb, col_w2, col_b2,
        ridx, cidx, gemb, gidx, Wout, ws);
    attn_kernel<<<Bb * NH * Hh * (Ww / 4), 256, 0, stream>>>(ws);
    outproj_kernel<<<Bb * Gg * HW / 16, 256, 0, stream>>>(bout, ws, out);
}

// Round 11
// 178.061 us; speedup vs baseline: 2.5728x; 1.0066x over previous
//
#include <hip/hip_runtime.h>
#include <math.h>

#define Bb   2
#define CIN  32
#define Gg   4
#define NH   4
#define Hh   28
#define Ww   28
#define HW   784
#define Pp   7
#define PP   49
#define MID  48
#define COUT 64
#define OC   192   // MID*NH

// workspace layout (units = u32 words / floats):
//   Qf16 [bh][g][ij][24 cpairs]   at QF    (8*4*784*24 = 602112)
//   Kf16 [bh][m][ij][24 cpairs]   at KF    (602112)
//   Vf16 [bh][mp][ij][48 ch]      at VF    (8*2*784*48 = 602112) m-pair packed
//   O f32 [b][v][ij][OC]          at OOFF  (1204224 floats)
#define QF    0
#define KF    602112
#define VF    1204224
#define OOFF  1806336
#define KBH   75264     // u32 per bh in K (4 m planes)
#define KM    18816     // u32 per m plane (784*24)
#define VBH   75264     // u32 per bh in V (2 planes)
#define VPL   37632     // u32 per V plane (784*48)

// 1/sqrt(32) * log2(e): K pre-scaled so softmax exp is a bare v_exp_f32.
#define KSCALE 0.2550611135387359f

// small precomputed tables (written by qkvpe's table block each call)
__device__ unsigned g_peT2[Gg * PP * 16];   // [v][kl][cpair(16)] — b128/lane coalesced
__device__ unsigned g_geT2[8 * 64];         // [cpair(8)][v*16+g*4+m], scaled
__device__ float    g_WT2[OC * COUT];       // [h*48+c][o], permuted Wout

typedef _Float16 h2f __attribute__((ext_vector_type(2)));

__device__ __forceinline__ unsigned packh2(float a, float b) {
    auto r = __builtin_amdgcn_cvt_pkrtz(a, b);    // v_cvt_pkrtz_f16_f32
    return __builtin_bit_cast(unsigned, r);
}

__device__ __forceinline__ float fdot2(unsigned a, unsigned b, float c) {
    return __builtin_amdgcn_fdot2(__builtin_bit_cast(h2f, a),
                                  __builtin_bit_cast(h2f, b), c, false);
}

__device__ __forceinline__ float exp2_fast(float x) {   // 2^x, exp2(-inf)=0
    float r;
    asm("v_exp_f32 %0, %1" : "=v"(r) : "v"(x));
    return r;
}

// ---------------------------------------------------------------- kernel 1
// QKV 1x1 conv, f16-packed output. Block = (b, g-pair, i, half-row of 14):
// 224 conv blocks + table block 224. ROUND-23: prep dispatch ELIMINATED —
// each conv block stages weights into wls directly from the ORIGINAL W
// layout: thread tid owns row oo = (tid%48)*4+tid/48 (32 contiguous floats
// = 8 float4 loads, unroll-2 so only 8 VGPR transiently live), scattered to
// wls[ci*193+tid] (odd stride, conflict-free). Same floats reach wls as the
// old prep permute -> bit-identical output; 24 load-instrs/thread vs 96;
// one fewer dispatch in the replay graph (r3=4-dispatch measured 169 vs
// r8/r10=5-dispatch at ~179.5 with individually-faster kernels).
// SESSION LAW (r15/r17/r7/r9): any structure that materializes a large pool
// of independent/loop-invariant values spills to scratch. Bulk data goes
// through LDS only; transient register windows stay <= ~8 regs.
__global__ __launch_bounds__(192) void qkvpe_kernel(const float* __restrict__ x,
    const float* __restrict__ Wq, const float* __restrict__ bq,
    const float* __restrict__ Wk, const float* __restrict__ bk,
    const float* __restrict__ Wv, const float* __restrict__ bv,
    const float* row_w1, const float* row_b1,
    const float* row_g,  const float* row_bb,
    const float* row_w2, const float* row_b2,
    const float* col_w1, const float* col_b1,
    const float* col_g,  const float* col_bb,
    const float* col_w2, const float* col_b2,
    const float* row_idx, const float* col_idx,
    const float* group_emb, const int* g_indices,
    const float* Wout,
    float* __restrict__ ws)
{
    __shared__ float xs[2 * CIN * 16];            // 4 KB: two g-planes, stride 16
    __shared__ float wls[32 * 193];               // 24.7 KB: weights [ci][t] (also table staging)
    int tid = threadIdx.x;
    unsigned* uw = (unsigned*)ws;
    if (blockIdx.x == Bb * 2 * Hh * 2) {
        // ---------------- table block ----------------
        for (int t = tid; t < 2 * Gg * PP; t += 192) {
            int half = t / (Gg * PP);
            int n    = t - half * (Gg * PP);      // v*49 + kl
            int v = n / PP, kl = n % PP;
            const float* w1 = half ? col_w1 : row_w1;
            const float* b1 = half ? col_b1 : row_b1;
            const float* lg = half ? col_g  : row_g;
            const float* lb = half ? col_bb : row_bb;
            const float* w2 = half ? col_w2 : row_w2;
            const float* b2 = half ? col_b2 : row_b2;
            float tv = half ? col_idx[n] : row_idx[n];

            float hb[16];
            float mean = 0.f;
            for (int k = 0; k < 16; k++) { hb[k] = tv * w1[k] + b1[k]; mean += hb[k]; }
            mean *= (1.f / 16.f);
            float var = 0.f;
            for (int k = 0; k < 16; k++) { float d = hb[k] - mean; var += d * d; }
            var *= (1.f / 16.f);
            float inv = 1.f / sqrtf(var + 1e-5f);
            for (int k = 0; k < 16; k++) {
                float hn = (hb[k] - mean) * inv * lg[k] + lb[k];
                hb[k] = hn / (1.f + expf(-hn));
            }
            float accv[16];
            for (int p = 0; p < 16; p++) {
                float acc = b2[p];
                for (int k = 0; k < 16; k++) acc += hb[k] * w2[p * 16 + k];
                accv[p] = acc * KSCALE;
            }
            for (int i2 = 0; i2 < 8; i2++)
                g_peT2[(v * PP + kl) * 16 + half * 8 + i2] =
                    packh2(accv[2 * i2], accv[2 * i2 + 1]);
        }
        for (int t = tid; t < 64; t += 192) {
            int gi = g_indices[t];
            for (int i2 = 0; i2 < 8; i2++)
                g_geT2[i2 * 64 + t] = packh2(group_emb[gi * 16 + 2 * i2] * KSCALE,
                                             group_emb[gi * 16 + 2 * i2 + 1] * KSCALE);
        }
        // g_WT2[tp*64+o] = Wout[o*192 + c*4+h] via LDS transpose (wls as staging)
        for (int chunk = 0; chunk < 4; chunk++) {
            int obase = chunk * 16;
            __syncthreads();
            for (int idx = tid; idx < 16 * OC; idx += 192) {
                int ol = idx / OC, t = idx % OC;
                wls[ol * 193 + t] = Wout[(obase + ol) * OC + t];   // coalesced
            }
            __syncthreads();
            for (int idx = tid; idx < 16 * OC; idx += 192) {
                int tp = idx / 16, ol = idx % 16;                   // ol fastest
                int h = tp / MID, c = tp % MID;
                g_WT2[tp * 64 + obase + ol] = wls[ol * 193 + c * NH + h];
            }
        }
        return;
    }

    // ---------------- QKV block: (b, gp, i, half-row of 14), 2 g-planes ----
    int r = blockIdx.x;
    int jh = r & 1; r >>= 1;
    int i = r % Hh; r /= Hh;
    int gp = r & 1; int b = r >> 1;
    int j0 = jh * 14;

    for (int idx = tid; idx < 2 * CIN * 14; idx += 192) {
        int gs = idx / (CIN * 14), rem = idx % (CIN * 14);
        int ci = rem / 14, jj = rem % 14;
        xs[gs * CIN * 16 + ci * 16 + jj] =
            x[((b * CIN + ci) * Gg + 2 * gp + gs) * HW + i * Ww + j0 + jj];
    }

    int h = tid / MID, c = tid % MID;             // stores coalesced in c
    int oo = c * NH + h;
    int bh = b * NH + h;
    int ij0 = i * Ww + j0;
    const float* xs0 = &xs[0];
    const float* xs1 = &xs[CIN * 16];

// LDS-weight conv body: 14 positions from one g-plane, acc array A
#define CONVW(A, XR)                                                          \
    {                                                                         \
        _Pragma("unroll")                                                     \
        for (int jj = 0; jj < 14; jj++) A[jj] = bias;                         \
        _Pragma("unroll 4")                                                   \
        for (int ci = 0; ci < 32; ci++) {                                     \
            float wv = wls[ci * 193 + tid];                                   \
            float4 xA = *(const float4*)&XR[ci * 16 + 0];                     \
            float4 xB = *(const float4*)&XR[ci * 16 + 4];                     \
            float4 xC = *(const float4*)&XR[ci * 16 + 8];                     \
            float2 xD = *(const float2*)&XR[ci * 16 + 12];                    \
            A[0] += wv * xA.x;  A[1] += wv * xA.y;  A[2] += wv * xA.z;        \
            A[3] += wv * xA.w;  A[4] += wv * xB.x;  A[5] += wv * xB.y;        \
            A[6] += wv * xB.z;  A[7] += wv * xB.w;  A[8] += wv * xC.x;        \
            A[9] += wv * xC.y;  A[10] += wv * xC.z; A[11] += wv * xC.w;       \
            A[12] += wv * xD.x; A[13] += wv * xD.y;                           \
        }                                                                     \
    }

    #pragma unroll 1
    for (int p = 0; p < 3; p++) {
        const float* Wm = (p == 0) ? Wq : (p == 1) ? Wk : Wv;
        float bias = ((p == 0) ? bq : (p == 1) ? bk : bv)[oo];
        const float4* Wr4 = (const float4*)(Wm + oo * CIN);   // thread's own row
        __syncthreads();                           // prev-p wls reads done (also covers xs stage at p=0)
        #pragma unroll 2
        for (int q = 0; q < 8; q++) {              // 8 b128 loads; <=8 VGPR live
            float4 wv4 = Wr4[q];
            wls[(q * 4 + 0) * 193 + tid] = wv4.x;
            wls[(q * 4 + 1) * 193 + tid] = wv4.y;
            wls[(q * 4 + 2) * 193 + tid] = wv4.z;
            wls[(q * 4 + 3) * 193 + tid] = wv4.w;
        }
        __syncthreads();                           // wls ready

        if (p < 2) {
            float scl = p ? KSCALE : 1.0f;
            int base0 = p ? KF : QF;
            #pragma unroll 1
            for (int gs = 0; gs < 2; gs++) {
                float a[14];
                CONVW(a, (gs ? xs1 : xs0))
                int ob = base0 + ((bh * Gg + 2 * gp + gs) * HW + ij0) * 24 + (c >> 1);
                #pragma unroll
                for (int jj = 0; jj < 14; jj++) {
                    float av = a[jj] * scl;
                    float pr = __shfl_xor(av, 1, 64);   // partner channel c^1
                    if (!(tid & 1)) uw[ob + jj * 24] = packh2(av, pr);
                }
            }
        } else {
            float a0[14], a1[14];
            CONVW(a0, xs0)
            CONVW(a1, xs1)
            int vb = VF + ((bh * 2 + gp) * HW + ij0) * 48 + c;
            #pragma unroll
            for (int jj = 0; jj < 14; jj++)
                uw[vb + jj * 48] = packh2(a0[jj], a1[jj]);   // m-pair (g0,g1)
        }
    }
#undef CONVW
}

// ---------------------------------------------------------------- kernel 2
// attention: block = 4 waves = positions (i, j0..j0+3) for one (b,h).
// r8-verified form: f16 ws staging, clamped addresses, pp2 prob transport
// through LDS (r9's register/shfl transport LICM-hoisted 392 broadcasts ->
// 680 MB scratch traffic; LDS is the only safe bulk path here).
__global__ __launch_bounds__(256, 4) void attn_kernel(float* __restrict__ ws)
{
    __shared__ __align__(16) unsigned kvb[7000];   // 28000 B: K [m][cell][25]; V planes [2][cell][48]
    __shared__ __align__(16) unsigned pp2[4][PP][8];   // 6272 B: [wave][kl][v*2+mp] f16-pair probs
    __shared__ __align__(16) unsigned qp[4][4][32];    // 2048 B: [wave][g][cpair 24, pad to 32]
    __shared__ __align__(16) float gsm[4][64];     //  1024 B: [wave][vg*4+m]

    const int tid  = threadIdx.x;
    const int wave = tid >> 6;
    const int lane = tid & 63;

    int blk = blockIdx.x;                  // ((bh)*28 + i)*7 + j0/4
    int j0 = (blk % 7) * 4;
    int i  = (blk / 7) % Hh;
    int bh = blk / (7 * Hh);
    int b = bh >> 2, h = bh & 3;
    int j  = j0 + wave;
    int ij = i * Ww + j;

    const unsigned* uw = (const unsigned*)ws;
    const unsigned* Kf = uw + KF + bh * KBH;
    const unsigned* Vf = uw + VF + bh * VBH;
    float* Ot = ws + OOFF;

    // ---- q f16 pairs straight from ws into per-wave LDS ----
    if (lane < 48) {
        int g = lane / 12, c4 = lane % 12;
        uint2 qv = *(const uint2*)&uw[QF + ((bh * Gg + g) * HW + ij) * 24 + c4 * 2];
        qp[wave][g][c4 * 2]     = qv.x;
        qp[wave][g][c4 * 2 + 1] = qv.y;
    }

    // ---- stage all-m K tile (f16 pairs in ws already): 420 slots of
    //      (cell, 8-channel chunk); clamped addresses, no zero-fill (OOB
    //      cells are masked to -inf downstream so garbage is harmless). ----
    #pragma unroll
    for (int s = 0; s < 2; s++) {
        int t = tid + s * 256;
        if (t < 420) {
            int c8 = t % 6, cl = t / 6;
            int gy = i - 3 + cl / 10, gx = j0 - 3 + cl % 10;
            gy = min(max(gy, 0), Hh - 1); gx = min(max(gx, 0), Ww - 1);
            const unsigned* kp = &Kf[(gy * Ww + gx) * 24 + c8 * 4];
            #pragma unroll
            for (int m = 0; m < 4; m++) {
                uint4 kv = *(const uint4*)(kp + m * KM);
                int o = (m * 70 + cl) * 25 + c8 * 4;
                *(uint2*)&kvb[o]     = make_uint2(kv.x, kv.y);
                *(uint2*)&kvb[o + 2] = make_uint2(kv.z, kv.w);
            }
        }
    }

    // ---- per-lane geometry (lane = kl) ----
    int kk = lane / Pp, ll = lane % Pp;
    int cell = (lane < PP) ? kk * 10 + ll + wave : 0;
    bool vmask = (lane < PP) && ((unsigned)(i + kk - 3) < Hh) && ((unsigned)(j + ll - 3) < Ww);
    int lclamp = lane < PP ? lane : 0;

    // ---- pe scores in registers; b128 q broadcasts + coalesced b128 peT2 ----
    float per[4][4] = {};                          // [v][g]
    #pragma unroll
    for (int u4 = 0; u4 < 4; u4++) {               // 4 cpairs per iter (c 0..31)
        uint4 qA = *(const uint4*)&qp[wave][0][u4 * 4];
        uint4 qB = *(const uint4*)&qp[wave][1][u4 * 4];
        uint4 qC = *(const uint4*)&qp[wave][2][u4 * 4];
        uint4 qD = *(const uint4*)&qp[wave][3][u4 * 4];
        #pragma unroll
        for (int v = 0; v < 4; v++) {
            uint4 pk = *(const uint4*)&g_peT2[(v * PP + lclamp) * 16 + u4 * 4];
            per[v][0] = fdot2(pk.w, qA.w, fdot2(pk.z, qA.z, fdot2(pk.y, qA.y, fdot2(pk.x, qA.x, per[v][0]))));
            per[v][1] = fdot2(pk.w, qB.w, fdot2(pk.z, qB.z, fdot2(pk.y, qB.y, fdot2(pk.x, qB.x, per[v][1]))));
            per[v][2] = fdot2(pk.w, qC.w, fdot2(pk.z, qC.z, fdot2(pk.y, qC.y, fdot2(pk.x, qC.x, per[v][2]))));
            per[v][3] = fdot2(pk.w, qD.w, fdot2(pk.z, qD.z, fdot2(pk.y, qD.y, fdot2(pk.x, qD.x, per[v][3]))));
        }
    }
    // fold the border/idle mask into per: exp2(-inf) = 0, so no per-term select
    if (!vmask) {
        #pragma unroll
        for (int v = 0; v < 4; v++)
            #pragma unroll
            for (int g = 0; g < 4; g++) per[v][g] = -INFINITY;
    }

    // ---- group scores: lane = vg*4+m; q pairs 16..23 (c 32..47) ----
    {
        int g = (lane >> 2) & 3;
        float ga = 0.f;
        #pragma unroll
        for (int u = 0; u < 8; u++)
            ga = fdot2(g_geT2[u * 64 + lane], qp[wave][g][16 + u], ga);
        gsm[wave][lane] = ga;
    }
    __syncthreads();                               // barrier 1: K tile ready

    // ---- content: b128 q broadcasts, b64 K reads; each K pair serves all 4 g ----
    float acc[4][4] = {};                          // [m][g]
    #pragma unroll 2
    for (int u4 = 0; u4 < 6; u4++) {               // 4 cpairs (8 channels) per iter
        uint4 qA = *(const uint4*)&qp[wave][0][u4 * 4];
        uint4 qB = *(const uint4*)&qp[wave][1][u4 * 4];
        uint4 qC = *(const uint4*)&qp[wave][2][u4 * 4];
        uint4 qD = *(const uint4*)&qp[wave][3][u4 * 4];
        #pragma unroll
        for (int m = 0; m < 4; m++) {
            int base = (m * 70 + cell) * 25 + u4 * 4;
            uint2 k01 = *(const uint2*)&kvb[base];
            uint2 k23 = *(const uint2*)&kvb[base + 2];
            acc[m][0] = fdot2(k23.y, qA.w, fdot2(k23.x, qA.z, fdot2(k01.y, qA.y, fdot2(k01.x, qA.x, acc[m][0]))));
            acc[m][1] = fdot2(k23.y, qB.w, fdot2(k23.x, qB.z, fdot2(k01.y, qB.y, fdot2(k01.x, qB.x, acc[m][1]))));
            acc[m][2] = fdot2(k23.y, qC.w, fdot2(k23.x, qC.z, fdot2(k01.y, qC.y, fdot2(k01.x, qC.x, acc[m][2]))));
            acc[m][3] = fdot2(k23.y, qD.w, fdot2(k23.x, qD.z, fdot2(k01.y, qD.y, fdot2(k01.x, qD.x, acc[m][3]))));
        }
    }

    // ---- softmax per (v,g); scores pre-scaled by log2e -> bare v_exp_f32 ----
    float ppr[4][4] = {};                          // [v][m]
    #pragma unroll
    for (int v = 0; v < 4; v++) {
        #pragma unroll
        for (int g = 0; g < 4; g++) {
            int vg = v * 4 + g;
            float4 gs = *(const float4*)&gsm[wave][vg * 4];   // b128 broadcast
            float ex[4];
            ex[0] = exp2_fast(acc[0][g] + per[v][g] + gs.x);
            ex[1] = exp2_fast(acc[1][g] + per[v][g] + gs.y);
            ex[2] = exp2_fast(acc[2][g] + per[v][g] + gs.z);
            ex[3] = exp2_fast(acc[3][g] + per[v][g] + gs.w);
            float ls = ex[0] + ex[1] + ex[2] + ex[3];
            #pragma unroll
            for (int d = 32; d > 0; d >>= 1) ls += __shfl_xor(ls, d, 64);
            float rinv = 1.0f / ls;
            #pragma unroll
            for (int m = 0; m < 4; m++) ppr[v][m] += ex[m] * rinv;
        }
    }
    // pack probs as f16 m-pairs: pp2[wave][kl][v*2+mp]
    if (lane < PP) {
        uint4 w0, w1;
        w0.x = packh2(ppr[0][0], ppr[0][1]); w0.y = packh2(ppr[0][2], ppr[0][3]);
        w0.z = packh2(ppr[1][0], ppr[1][1]); w0.w = packh2(ppr[1][2], ppr[1][3]);
        w1.x = packh2(ppr[2][0], ppr[2][1]); w1.y = packh2(ppr[2][2], ppr[2][3]);
        w1.z = packh2(ppr[3][0], ppr[3][1]); w1.w = packh2(ppr[3][2], ppr[3][3]);
        *(uint4*)&pp2[wave][lane][0] = w0;
        *(uint4*)&pp2[wave][lane][4] = w1;
    }
    __syncthreads();                               // barrier 2: K reads done

    // ---- stage all-m V (f16 in ws already): direct load->LDS, both planes ----
    for (int t = tid; t < 840; t += 256) {
        int c4 = t % 12, cl = t / 12;
        int gy = i - 3 + cl / 10, gx = j0 - 3 + cl % 10;
        gy = min(max(gy, 0), Hh - 1); gx = min(max(gx, 0), Ww - 1);
        int off = (gy * Ww + gx) * 48 + c4 * 4;
        uint4 A = *(const uint4*)&Vf[off];
        uint4 B = *(const uint4*)&Vf[VPL + off];
        int o = cl * 48 + c4 * 4;
        *(uint4*)&kvb[o]        = A;
        *(uint4*)&kvb[3360 + o] = B;
    }
    __syncthreads();                               // barrier 3: V tile ready

    // ---- PV: lane = c (<48); two b32 plane reads (<=2-way, free) + 2 b128
    //      prob broadcasts per cell; fully unrolled -> all-immediate offsets ----
    if (lane < MID) {
        float o0 = 0.f, o1 = 0.f, o2 = 0.f, o3 = 0.f;
        const uint4* ppw = (const uint4*)&pp2[wave][0][0];
        const unsigned* v0b = &kvb[wave * 48 + lane];        // plane0 (m01)
        const unsigned* v1b = v0b + 3360;                    // plane1 (m23)
        #pragma unroll
        for (int kl2 = 0; kl2 < PP; kl2++) {
            int cellc = (kl2 / Pp) * 10 + (kl2 % Pp);        // compile-time
            unsigned vv0 = v0b[cellc * 48];
            unsigned vv1 = v1b[cellc * 48];
            uint4 A = ppw[kl2 * 2];
            uint4 B = ppw[kl2 * 2 + 1];
            o0 = fdot2(vv1, A.y, fdot2(vv0, A.x, o0));
            o1 = fdot2(vv1, A.w, fdot2(vv0, A.z, o1));
            o2 = fdot2(vv1, B.y, fdot2(vv0, B.x, o2));
            o3 = fdot2(vv1, B.w, fdot2(vv0, B.z, o3));
        }
        Ot[((size_t)(b * Gg + 0) * HW + ij) * OC + h * MID + lane] = o0;
        Ot[((size_t)(b * Gg + 1) * HW + ij) * OC + h * MID + lane] = o1;
        Ot[((size_t)(b * Gg + 2) * HW + ij) * OC + h * MID + lane] = o2;
        Ot[((size_t)(b * Gg + 3) * HW + ij) * OC + h * MID + lane] = o3;
    }
}

// ---------------------------------------------------------------- kernel 3
__global__ __launch_bounds__(256) void outproj_kernel(const float* __restrict__ bout,
                                                      const float* __restrict__ ws,
                                                      float* __restrict__ out)
{
    __shared__ float ov[16 * 193];
    __shared__ float res[64 * 17];
    int tid = threadIdx.x;
    int p0 = blockIdx.x * 16;
    const float* Ot = ws + OOFF;

    for (int idx = tid; idx < 16 * OC; idx += 256) {
        int pl = idx / OC, t = idx % OC;
        ov[pl * 193 + t] = Ot[(size_t)(p0 + pl) * OC + t];
    }
    __syncthreads();

    int o = tid & 63, pg = tid >> 6;
    float a0 = bout[o], a1 = a0, a2 = a0, a3 = a0;
    #pragma unroll 8
    for (int t = 0; t < OC; t++) {
        float w = g_WT2[t * 64 + o];
        a0 += w * ov[(pg     ) * 193 + t];
        a1 += w * ov[(pg +  4) * 193 + t];
        a2 += w * ov[(pg +  8) * 193 + t];
        a3 += w * ov[(pg + 12) * 193 + t];
    }
    res[o * 17 + pg     ] = a0;
    res[o * 17 + pg +  4] = a1;
    res[o * 17 + pg +  8] = a2;
    res[o * 17 + pg + 12] = a3;
    __syncthreads();

    for (int idx = tid; idx < 1024; idx += 256) {
        int o2 = idx >> 4, pl = idx & 15;
        int p = p0 + pl;
        int ij2 = p % HW; int bv = p / HW; int v = bv & 3; int bb = bv >> 2;
        out[((bb * COUT + o2) * Gg + v) * HW + ij2] = res[o2 * 17 + pl];
    }
}

// ---------------------------------------------------------------- launch
extern "C" void kernel_launch(void* const* d_in, const int* in_sizes, int n_in,
                              void* d_out, int out_size, void* d_ws, size_t ws_size,
                              hipStream_t stream)
{
    const float* x      = (const float*)d_in[0];
    const float* Wq     = (const float*)d_in[1];
    const float* bq     = (const float*)d_in[2];
    const float* Wk     = (const float*)d_in[3];
    const float* bk     = (const float*)d_in[4];
    const float* Wv     = (const float*)d_in[5];
    const float* bv     = (const float*)d_in[6];
    const float* Wout   = (const float*)d_in[7];
    const float* bout   = (const float*)d_in[8];
    const float* row_w1 = (const float*)d_in[9];
    const float* row_b1 = (const float*)d_in[10];
    const float* row_g  = (const float*)d_in[11];
    const float* row_bb = (const float*)d_in[12];
    const float* row_w2 = (const float*)d_in[13];
    const float* row_b2 = (const float*)d_in[14];
    const float* col_w1 = (const float*)d_in[15];
    const float* col_b1 = (const float*)d_in[16];
    const float* col_g  = (const float*)d_in[17];
    const float* col_bb = (const float*)d_in[18];
    const float* col_w2 = (const float*)d_in[19];
    const float* col_b2 = (const float*)d_in[20];
    const float* gemb   = (const float*)d_in[21];
    const float* ridx   = (const float*)d_in[22];
    const float* cidx   = (const float*)d_in[23];
    const int*   gidx   = (const int*)d_in[24];

    float* ws  = (float*)d_ws;
    float* out = (float*)d_out;

    qkvpe_kernel<<<Bb * 2 * Hh * 2 + 1, 192, 0, stream>>>(
        x, Wq, bq, Wk, bk, Wv, bv,
        row_w1, row_b1, row_g, row_bb, row_w2, row_b2,
        col_w1, col_b1, col_g, col_bb, col_w2, col_b2,
        ridx, cidx, gemb, gidx, Wout, ws);
    attn_kernel<<<Bb * NH * Hh * (Ww / 4), 256, 0, stream>>>(ws);
    outproj_kernel<<<Bb * Gg * HW / 16, 256, 0, stream>>>(bout, ws, out);
}